// Round 21
// baseline (86.579 us; speedup 1.0000x reference)
//
#include <hip/hip_runtime.h>
#include <math.h>

// ---------------------------------------------------------------------------
// mLSTM cell, MFMA bf16. Round 21: R20 + equal-depth co-residency. Grid 1024
// = exactly 4 blocks/CU (bids c, c+256, c+512, c+768 <=> u +32 apart). Map
// u -> (band, half) so all four co-resident blocks have the SAME chain depth:
// r=u&31, s=u>>5, band=62-2r+(s>>1), half=s&1. Critical CU keeps 4-block
// overlap its whole run + its blocks stream the same K/V tiles (L2 hits).
// Everything else identical to R20 (best: 81.4us).
// ---------------------------------------------------------------------------

#define BB   2
#define SS   2048
#define DD   1024
#define NHH  4
#define DHH  256
#define BHH  (BB*NHH)

// Workspace byte offsets (~49 MB; ACC0 overlays dead KB)
#define QB_OFF   ((size_t)0)
#define KB_OFF   ((size_t)8  << 20)
#define VB_OFF   ((size_t)16 << 20)
#define KF_OFF   ((size_t)24 << 20)
#define VF_OFF   ((size_t)32 << 20)
#define ACC0_OFF ((size_t)8  << 20)   // 8 MB bf16, overlays KB (dead after k_pack)
#define ACC1_OFF ((size_t)40 << 20)   // 8 MB bf16
#define DEN_OFF  ((size_t)48 << 20)   // 512 KB
#define IG_OFF   (DEN_OFF + ((size_t)512<<10))
#define LSF_OFF  (IG_OFF  + ((size_t)64<<10))
#define AA_OFF   (LSF_OFF + ((size_t)64<<10))
#define MM_OFF   (AA_OFF  + ((size_t)64<<10))
#define FLR_OFF  (MM_OFF  + ((size_t)64<<10))
#define WSI_OFF  (FLR_OFF + ((size_t)64<<10))
#define WSF_OFF  (WSI_OFF + ((size_t)32<<10))

typedef __attribute__((ext_vector_type(8))) short short8;   // 8 bf16 (4 VGPR)
typedef __attribute__((ext_vector_type(4))) float f32x4;

__device__ __forceinline__ unsigned short f2b(float f) {
  union { float f; unsigned int u; } v; v.f = f;
  unsigned int r = (v.u + 0x7FFFu + ((v.u >> 16) & 1u)) >> 16;
  return (unsigned short)r;
}
__device__ __forceinline__ float b2f(unsigned short u) {
  union { float f; unsigned int u32; } v; v.u32 = ((unsigned int)u) << 16;
  return v.f;
}
__device__ __forceinline__ float dot4(float4 a, float4 b) {
  return a.x*b.x + a.y*b.y + a.z*b.z + a.w*b.w;
}

// ---------------------------------------------------------------------------
// Kernel 0: gate weight pre-sum.
// ---------------------------------------------------------------------------
__global__ __launch_bounds__(256) void k_gw(
    const float* __restrict__ wi, const float* __restrict__ wf,
    float* __restrict__ wsi, float* __restrict__ wsf)
{
  const int idx = blockIdx.x*256 + threadIdx.x;   // 0..8191
  const int n = idx >> 10, c = idx & 1023;
  wsi[idx] = wi[n*3*DD + c] + wi[n*3*DD + DD + c] + wi[n*3*DD + 2*DD + c];
  wsf[idx] = wf[n*3*DD + c] + wf[n*3*DD + DD + c] + wf[n*3*DD + 2*DD + c];
}

// ---------------------------------------------------------------------------
// Kernel 1: headwise QKV projection + gate GEMVs, 8 rows/block.
// ---------------------------------------------------------------------------
__global__ __launch_bounds__(256) void k_proj(
    const float* __restrict__ x,
    const float* __restrict__ wq, const float* __restrict__ wk, const float* __restrict__ wv,
    const float* __restrict__ wsi, const float* __restrict__ bi,
    const float* __restrict__ wsf, const float* __restrict__ bf,
    unsigned short* __restrict__ qb, unsigned short* __restrict__ kb,
    unsigned short* __restrict__ vb, float* __restrict__ ig, float* __restrict__ lsf)
{
  const int rb = blockIdx.x;           // 0..511, 8 rows each
  const int g  = threadIdx.x;          // qkv head 0..255
  const int h   = g >> 6;
  const int dh0 = (g & 63) << 2;
  const int c   = g << 2;
  const int lane = g & 63, wid = g >> 6;

  const float4 q0 = *(const float4*)(wq + g*16 + 0);
  const float4 q1 = *(const float4*)(wq + g*16 + 4);
  const float4 q2 = *(const float4*)(wq + g*16 + 8);
  const float4 q3 = *(const float4*)(wq + g*16 + 12);
  const float4 k0 = *(const float4*)(wk + g*16 + 0);
  const float4 k1 = *(const float4*)(wk + g*16 + 4);
  const float4 k2 = *(const float4*)(wk + g*16 + 8);
  const float4 k3 = *(const float4*)(wk + g*16 + 12);
  const float4 v0 = *(const float4*)(wv + g*16 + 0);
  const float4 v1 = *(const float4*)(wv + g*16 + 4);
  const float4 v2 = *(const float4*)(wv + g*16 + 8);
  const float4 v3 = *(const float4*)(wv + g*16 + 12);
  const float4 gi0 = *(const float4*)(wsi + 0*DD + c);
  const float4 gi1 = *(const float4*)(wsi + 1*DD + c);
  const float4 gi2 = *(const float4*)(wsi + 2*DD + c);
  const float4 gi3 = *(const float4*)(wsi + 3*DD + c);
  const float4 gf0 = *(const float4*)(wsf + 0*DD + c);
  const float4 gf1 = *(const float4*)(wsf + 1*DD + c);
  const float4 gf2 = *(const float4*)(wsf + 2*DD + c);
  const float4 gf3 = *(const float4*)(wsf + 3*DD + c);

  __shared__ float redI[8][4][4];   // [row][n][wid]
  __shared__ float redF[8][4][4];

  #pragma unroll
  for (int r4 = 0; r4 < 8; ++r4) {
    const int row = rb*8 + r4;
    const int b = row >> 11, s = row & (SS-1);
    const float4 xv = *(const float4*)(x + (size_t)row*DD + c);
    const size_t qi = ((size_t)(b*NHH + h)*SS + s)*DHH + dh0;

    ushort4 r;
    r.x = f2b(dot4(q0,xv)); r.y = f2b(dot4(q1,xv));
    r.z = f2b(dot4(q2,xv)); r.w = f2b(dot4(q3,xv));
    *(ushort4*)(qb + qi) = r;
    r.x = f2b(0.0625f*dot4(k0,xv)); r.y = f2b(0.0625f*dot4(k1,xv));
    r.z = f2b(0.0625f*dot4(k2,xv)); r.w = f2b(0.0625f*dot4(k3,xv));
    *(ushort4*)(kb + qi) = r;
    r.x = f2b(dot4(v0,xv)); r.y = f2b(dot4(v1,xv));
    r.z = f2b(dot4(v2,xv)); r.w = f2b(dot4(v3,xv));
    *(ushort4*)(vb + qi) = r;

    float pi0 = dot4(gi0,xv), pi1 = dot4(gi1,xv), pi2 = dot4(gi2,xv), pi3 = dot4(gi3,xv);
    float pf0 = dot4(gf0,xv), pf1 = dot4(gf1,xv), pf2 = dot4(gf2,xv), pf3 = dot4(gf3,xv);
    #pragma unroll
    for (int off=32; off>0; off>>=1) {
      pi0 += __shfl_down(pi0, off); pi1 += __shfl_down(pi1, off);
      pi2 += __shfl_down(pi2, off); pi3 += __shfl_down(pi3, off);
      pf0 += __shfl_down(pf0, off); pf1 += __shfl_down(pf1, off);
      pf2 += __shfl_down(pf2, off); pf3 += __shfl_down(pf3, off);
    }
    if (lane == 0) {
      redI[r4][0][wid] = pi0; redI[r4][1][wid] = pi1;
      redI[r4][2][wid] = pi2; redI[r4][3][wid] = pi3;
      redF[r4][0][wid] = pf0; redF[r4][1][wid] = pf1;
      redF[r4][2][wid] = pf2; redF[r4][3][wid] = pf3;
    }
  }
  __syncthreads();
  if (g < 32) {
    const int r4 = g >> 2, n = g & 3;
    const int row = rb*8 + r4;
    const int b = row >> 11, s = row & (SS-1);
    float ti = redI[r4][n][0]+redI[r4][n][1]+redI[r4][n][2]+redI[r4][n][3] + bi[n];
    float tf = redF[r4][n][0]+redF[r4][n][1]+redF[r4][n][2]+redF[r4][n][3] + bf[n];
    ig[(size_t)(b*NHH+n)*SS + s] = ti;
    float ls = (tf >= 0.f) ? -log1pf(expf(-tf)) : (tf - log1pf(expf(tf)));
    lsf[(size_t)(b*NHH+n)*SS + s] = ls;
  }
}

// ---------------------------------------------------------------------------
// Kernel 2: per-(b,head) scan.
// ---------------------------------------------------------------------------
__global__ __launch_bounds__(256) void k_scan(
    const float* __restrict__ ig, const float* __restrict__ lsf,
    float* __restrict__ aa, float* __restrict__ mm, float* __restrict__ flr)
{
  const int bh = blockIdx.x;
  const int tid = threadIdx.x;
  const float* igp = ig + (size_t)bh*SS;
  const float* lsp = lsf + (size_t)bh*SS;
  float* ap = aa + (size_t)bh*SS;
  float* mp = mm + (size_t)bh*SS;
  float* fp = flr + (size_t)bh*SS;

  __shared__ float sb[256];
  const int base = tid*8;
  float l[8], c[8];
  #pragma unroll
  for (int j=0;j<8;j++) l[j] = lsp[base+j];
  c[0] = l[0];
  #pragma unroll
  for (int j=1;j<8;j++) c[j] = c[j-1] + l[j];

  sb[tid] = c[7];
  __syncthreads();
  for (int off=1; off<256; off<<=1) {
    float v = sb[tid];
    float u = (tid>=off) ? sb[tid-off] : 0.f;
    __syncthreads();
    sb[tid] = v + u;
    __syncthreads();
  }
  const float exs = (tid==0) ? 0.f : sb[tid-1];

  float cs[8], a8[8], mx[8];
  #pragma unroll
  for (int j=0;j<8;j++) { cs[j] = exs + c[j]; a8[j] = igp[base+j] - cs[j]; }
  mx[0] = a8[0];
  #pragma unroll
  for (int j=1;j<8;j++) mx[j] = fmaxf(mx[j-1], a8[j]);

  __syncthreads();
  sb[tid] = mx[7];
  __syncthreads();
  for (int off=1; off<256; off<<=1) {
    float v = sb[tid];
    float u = (tid>=off) ? sb[tid-off] : -INFINITY;
    __syncthreads();
    sb[tid] = fmaxf(v, u);
    __syncthreads();
  }
  const float exm = (tid==0) ? -INFINITY : sb[tid-1];

  #pragma unroll
  for (int j=0;j<8;j++) {
    float mmx = fmaxf(exm, mx[j]);
    ap[base+j] = a8[j];
    mp[base+j] = mmx;
    fp[base+j] = expf(-(cs[j] + mmx));
  }
}

// ---------------------------------------------------------------------------
// Kernel 3: fused fragment-stream pack (K then V through the same LDS tile).
// ---------------------------------------------------------------------------
__global__ __launch_bounds__(256) void k_pack(
    const unsigned short* __restrict__ kb, const unsigned short* __restrict__ vb,
    unsigned short* __restrict__ kfo, unsigned short* __restrict__ vfo)
{
  __shared__ unsigned short tile[64][264];
  const int bh = blockIdx.x, kt = blockIdx.y;
  const int t0 = kt*64;
  const int tid = threadIdx.x;

  // ---- K ----
  #pragma unroll
  for (int i=0;i<8;i++){
    int f = tid + i*256;
    int r = f >> 5, c = (f & 31)*8;
    *(uint4*)&tile[r][c] = *(const uint4*)(kb + ((size_t)bh*SS + t0 + r)*DHH + c);
  }
  __syncthreads();
  {
    unsigned short* dst = kfo + (size_t)(bh*32 + kt)*16384;
    #pragma unroll
    for (int i=0;i<8;i++){
      int o = tid + i*256;
      int lane = o & 63, g = o >> 6;
      int tt = g >> 3, ks = g & 7;
      int l15 = lane & 15, lg = (lane >> 4) & 3;
      *(uint4*)(dst + (size_t)o*8) = *(const uint4*)&tile[16*tt + l15][32*ks + 8*lg];
    }
  }
  __syncthreads();

  // ---- V ----
  #pragma unroll
  for (int i=0;i<8;i++){
    int f = tid + i*256;
    int r = f >> 5, c = (f & 31)*8;
    *(uint4*)&tile[r][c] = *(const uint4*)(vb + ((size_t)bh*SS + t0 + r)*DHH + c);
  }
  __syncthreads();
  {
    unsigned short* dst = vfo + (size_t)(bh*32 + kt)*16384;
    #pragma unroll
    for (int i=0;i<8;i++){
      int o = tid + i*256;
      int lane = o & 63, g = o >> 6;
      int wc = g >> 3, fi = g & 7;
      int kst = fi >> 2, nt = fi & 3;
      int l15 = lane & 15, lg = (lane >> 4) & 3;
      unsigned short tmp[8];
      #pragma unroll
      for (int j=0;j<8;j++)
        tmp[j] = tile[32*kst + 8*lg + j][64*wc + 16*nt + l15];
      *(uint4*)(dst + (size_t)o*8) = *(uint4*)tmp;
    }
  }
}

// ---------------------------------------------------------------------------
// Kernel 4: MFMA attention, 32-row bands + split-K halves, W double-buffer,
// ONE lgkm-only barrier per tile. 1024 blocks x 256 thr (4 waves).
// Equal-depth co-residency: r=u&31, s=u>>5, band=62-2r+(s>>1), half=s&1.
// bf16 partial outputs (acc) + fp32 den partials.
// ---------------------------------------------------------------------------
__global__ __launch_bounds__(256) void k_attn(
    const unsigned short* __restrict__ qb, const unsigned short* __restrict__ kfr,
    const unsigned short* __restrict__ vfr,
    const float* __restrict__ ab, const float* __restrict__ mb,
    unsigned short* __restrict__ acc0, unsigned short* __restrict__ acc1,
    float* __restrict__ den)
{
  __shared__ __align__(16) char smW[2*32*128];   // W dbuf: 2 x 32 rows x 128B

  const int bid = blockIdx.x;
  const int bh  = bid & 7;                 // XCD pin
  const int u   = bid >> 3;                // 0..127
  const int rr_ = u & 31, s_ = u >> 5;
  const int band = 62 - 2*rr_ + (s_ >> 1); // co-residents: {2m,2m+1}x{h0,h1}
  const int half = s_ & 1;
  const int blk01 = bh*64 + band;
  const int s0  = band * 32;
  const int nkt = (32*band + 95) >> 6;     // 1..32
  const int n0  = (nkt + 1) >> 1;
  const int kbeg = half ? n0 : 0;
  const int kend = half ? nkt : n0;

  const int tid  = threadIdx.x;
  const int lane = tid & 63;
  const int wc   = tid >> 6;               // wave 0..3
  const int l15  = lane & 15, lg = lane >> 4;
  const int bhoff = bh * SS;
  const int trel = 16*wc + l15;

  const unsigned short* kfh = kfr + (size_t)bh*32*16384;
  const unsigned short* vfh = vfr + (size_t)bh*32*16384;

  // Q register-resident: 32 rows (two 16-row sub-bands mt)
  short8 qf[2][8];
  {
    const unsigned short* qp = qb + ((size_t)bh*SS + s0)*DHH;
    #pragma unroll
    for (int mt=0; mt<2; ++mt)
      #pragma unroll
      for (int ks=0; ks<8; ++ks)
        qf[mt][ks] = *(const short8*)(qp + (16*mt + l15)*DHH + 32*ks + 8*lg);
  }
  float mrow[2][4];
  #pragma unroll
  for (int mt=0; mt<2; ++mt)
    #pragma unroll
    for (int rr=0; rr<4; ++rr)
      mrow[mt][rr] = mb[bhoff + s0 + 16*mt + 4*lg + rr];

  f32x4 oacc[2][4];
  #pragma unroll
  for (int mt=0; mt<2; ++mt)
    #pragma unroll
    for (int nt=0; nt<4; ++nt)
      oacc[mt][nt] = (f32x4){0.f,0.f,0.f,0.f};
  float denp[2][4] = {{0.f,0.f,0.f,0.f},{0.f,0.f,0.f,0.f}};

  for (int kt = kbeg; kt < kend; ++kt) {
    const int t0 = kt*64;
    char* smWc = smW + ((kt&1)<<12);        // this tile's W slot

    // ---- V(kt) fragment stream + av FIRST (overlap kf latency) ----
    const unsigned short* vfp = vfh + (size_t)kt*16384 + (size_t)wc*4096 + lane*8;
    short8 v0 = *(const short8*)(vfp + 0*512);
    short8 v1 = *(const short8*)(vfp + 1*512);
    short8 v2 = *(const short8*)(vfp + 2*512);
    short8 v3 = *(const short8*)(vfp + 3*512);
    short8 v4 = *(const short8*)(vfp + 4*512);
    short8 v5 = *(const short8*)(vfp + 5*512);
    short8 v6 = *(const short8*)(vfp + 6*512);
    short8 v7 = *(const short8*)(vfp + 7*512);
    const float avC = ab[bhoff + t0 + trel];
    __builtin_amdgcn_sched_barrier(0);   // pin V issue before kf loads

    // ---- QK: kf stream (8 x 1KB coalesced), 16 MFMA (mt=0,1) ----
    f32x4 sacc0 = (f32x4){0.f,0.f,0.f,0.f};
    f32x4 sacc1 = (f32x4){0.f,0.f,0.f,0.f};
    {
      const unsigned short* kfp = kfh + (size_t)kt*16384 + (size_t)wc*4096 + lane*8;
      short8 k0 = *(const short8*)(kfp + 0*512);
      short8 k1 = *(const short8*)(kfp + 1*512);
      short8 k2 = *(const short8*)(kfp + 2*512);
      short8 k3 = *(const short8*)(kfp + 3*512);
      short8 k4 = *(const short8*)(kfp + 4*512);
      short8 k5 = *(const short8*)(kfp + 5*512);
      short8 k6 = *(const short8*)(kfp + 6*512);
      short8 k7 = *(const short8*)(kfp + 7*512);
      __builtin_amdgcn_s_setprio(1);
      sacc0 = __builtin_amdgcn_mfma_f32_16x16x32_bf16(qf[0][0], k0, sacc0, 0,0,0);
      sacc1 = __builtin_amdgcn_mfma_f32_16x16x32_bf16(qf[1][0], k0, sacc1, 0,0,0);
      sacc0 = __builtin_amdgcn_mfma_f32_16x16x32_bf16(qf[0][1], k1, sacc0, 0,0,0);
      sacc1 = __builtin_amdgcn_mfma_f32_16x16x32_bf16(qf[1][1], k1, sacc1, 0,0,0);
      sacc0 = __builtin_amdgcn_mfma_f32_16x16x32_bf16(qf[0][2], k2, sacc0, 0,0,0);
      sacc1 = __builtin_amdgcn_mfma_f32_16x16x32_bf16(qf[1][2], k2, sacc1, 0,0,0);
      sacc0 = __builtin_amdgcn_mfma_f32_16x16x32_bf16(qf[0][3], k3, sacc0, 0,0,0);
      sacc1 = __builtin_amdgcn_mfma_f32_16x16x32_bf16(qf[1][3], k3, sacc1, 0,0,0);
      sacc0 = __builtin_amdgcn_mfma_f32_16x16x32_bf16(qf[0][4], k4, sacc0, 0,0,0);
      sacc1 = __builtin_amdgcn_mfma_f32_16x16x32_bf16(qf[1][4], k4, sacc1, 0,0,0);
      sacc0 = __builtin_amdgcn_mfma_f32_16x16x32_bf16(qf[0][5], k5, sacc0, 0,0,0);
      sacc1 = __builtin_amdgcn_mfma_f32_16x16x32_bf16(qf[1][5], k5, sacc1, 0,0,0);
      sacc0 = __builtin_amdgcn_mfma_f32_16x16x32_bf16(qf[0][6], k6, sacc0, 0,0,0);
      sacc1 = __builtin_amdgcn_mfma_f32_16x16x32_bf16(qf[1][6], k6, sacc1, 0,0,0);
      sacc0 = __builtin_amdgcn_mfma_f32_16x16x32_bf16(qf[0][7], k7, sacc0, 0,0,0);
      sacc1 = __builtin_amdgcn_mfma_f32_16x16x32_bf16(qf[1][7], k7, sacc1, 0,0,0);
      __builtin_amdgcn_s_setprio(0);
    }

    // ---- W = mask * qk * exp(a[t]-m[s]) -> bf16 swizzled LDS slot kt&1 ----
    {
      const bool lastt = (kt == nkt-1);
      #pragma unroll
      for (int mt=0; mt<2; ++mt) {
        #pragma unroll
        for (int rr=0; rr<4; ++rr) {
          const int rib = 16*mt + 4*lg + rr;     // 0..31
          float wv = (mt ? sacc1[rr] : sacc0[rr]) * __expf(avC - mrow[mt][rr]);
          if (lastt && (t0 + trel > s0 + rib)) wv = 0.f;
          denp[mt][rr] += wv;
          *(unsigned short*)(smWc + (size_t)rib*128 + (((trel >> 3) ^ (rib & 7))<<4)
                              + ((trel & 7)<<1)) = f2b(wv);
        }
      }
    }

    // ---- pin V (crosses the barrier) ----
    asm volatile("" :: "v"((int)v0[0]), "v"((int)v1[0]), "v"((int)v2[0]),
                       "v"((int)v3[0]), "v"((int)v4[0]), "v"((int)v5[0]),
                       "v"((int)v6[0]), "v"((int)v7[0]));
    asm volatile("s_waitcnt lgkmcnt(0)" ::: "memory");
    __builtin_amdgcn_s_barrier();
    asm volatile("" ::: "memory");

    // ---- PV: W from LDS slot kt&1 + V from registers, 16 MFMA ----
    // (no trailing barrier: W(kt+2) reuses this slot only after bar(kt+1))
    {
      const int sr0 = l15, sr1 = 16 + l15;
      short8 w00 = *(const short8*)(smWc + (size_t)sr0*128 + ((lg^(sr0&7))<<4));
      short8 w10 = *(const short8*)(smWc + (size_t)sr1*128 + ((lg^(sr1&7))<<4));
      short8 w01 = *(const short8*)(smWc + (size_t)sr0*128 + (((4+lg)^(sr0&7))<<4));
      short8 w11 = *(const short8*)(smWc + (size_t)sr1*128 + (((4+lg)^(sr1&7))<<4));
      __builtin_amdgcn_s_setprio(1);
      oacc[0][0] = __builtin_amdgcn_mfma_f32_16x16x32_bf16(w00, v0, oacc[0][0], 0,0,0);
      oacc[1][0] = __builtin_amdgcn_mfma_f32_16x16x32_bf16(w10, v0, oacc[1][0], 0,0,0);
      oacc[0][1] = __builtin_amdgcn_mfma_f32_16x16x32_bf16(w00, v1, oacc[0][1], 0,0,0);
      oacc[1][1] = __builtin_amdgcn_mfma_f32_16x16x32_bf16(w10, v1, oacc[1][1], 0,0,0);
      oacc[0][2] = __builtin_amdgcn_mfma_f32_16x16x32_bf16(w00, v2, oacc[0][2], 0,0,0);
      oacc[1][2] = __builtin_amdgcn_mfma_f32_16x16x32_bf16(w10, v2, oacc[1][2], 0,0,0);
      oacc[0][3] = __builtin_amdgcn_mfma_f32_16x16x32_bf16(w00, v3, oacc[0][3], 0,0,0);
      oacc[1][3] = __builtin_amdgcn_mfma_f32_16x16x32_bf16(w10, v3, oacc[1][3], 0,0,0);
      oacc[0][0] = __builtin_amdgcn_mfma_f32_16x16x32_bf16(w01, v4, oacc[0][0], 0,0,0);
      oacc[1][0] = __builtin_amdgcn_mfma_f32_16x16x32_bf16(w11, v4, oacc[1][0], 0,0,0);
      oacc[0][1] = __builtin_amdgcn_mfma_f32_16x16x32_bf16(w01, v5, oacc[0][1], 0,0,0);
      oacc[1][1] = __builtin_amdgcn_mfma_f32_16x16x32_bf16(w11, v5, oacc[1][1], 0,0,0);
      oacc[0][2] = __builtin_amdgcn_mfma_f32_16x16x32_bf16(w01, v6, oacc[0][2], 0,0,0);
      oacc[1][2] = __builtin_amdgcn_mfma_f32_16x16x32_bf16(w11, v6, oacc[1][2], 0,0,0);
      oacc[0][3] = __builtin_amdgcn_mfma_f32_16x16x32_bf16(w01, v7, oacc[0][3], 0,0,0);
      oacc[1][3] = __builtin_amdgcn_mfma_f32_16x16x32_bf16(w11, v7, oacc[1][3], 0,0,0);
      __builtin_amdgcn_s_setprio(0);
    }
  }

  // ---- output: den partials (lane-reduced, fp32) + bf16 oacc, coalesced ----
  #pragma unroll
  for (int mt=0; mt<2; ++mt)
    #pragma unroll
    for (int rr=0; rr<4; ++rr) {
      float v = denp[mt][rr];
      v += __shfl_xor(v, 1); v += __shfl_xor(v, 2);
      v += __shfl_xor(v, 4); v += __shfl_xor(v, 8);
      if (l15 == 0)
        den[(((size_t)half*512 + blk01)*4 + wc)*32 + 16*mt + 4*lg + rr] = v;
    }
  unsigned short* accp = half ? acc1 : acc0;
  #pragma unroll
  for (int mt=0; mt<2; ++mt)
    #pragma unroll
    for (int nt=0; nt<4; ++nt) {
      ushort4 r;
      r.x = f2b(oacc[mt][nt][0]); r.y = f2b(oacc[mt][nt][1]);
      r.z = f2b(oacc[mt][nt][2]); r.w = f2b(oacc[mt][nt][3]);
      *(ushort4*)(accp + (((size_t)blk01*8 + mt*4 + nt)*256 + tid)*4) = r;
    }
}

// ---------------------------------------------------------------------------
// Kernel 5: combine halves + normalizer + per-head LayerNorm + write.
// ---------------------------------------------------------------------------
__global__ __launch_bounds__(256) void k_fin(
    const unsigned short* __restrict__ acc0, const unsigned short* __restrict__ acc1,
    const float* __restrict__ den,
    const float* __restrict__ flr, const float* __restrict__ ln_w,
    float* __restrict__ out)
{
  __shared__ float smS1[32*4];
  __shared__ float smS2[32*4];

  const int bid = blockIdx.x;              // 0..511
  const int bh = bid & 7, band = bid >> 3; // band 0..63
  const int blk01 = bh*64 + band;
  const int s0 = band*32;
  const int tid = threadIdx.x;
  const int lane = tid & 63, wc = tid >> 6;
  const int l15 = lane & 15, lg = lane >> 4;
  const int bhoff = bh*SS;
  const int bB = bh >> 2, h = bh & 3;

  f32x4 oacc[2][4];
  #pragma unroll
  for (int mt=0; mt<2; ++mt)
    #pragma unroll
    for (int nt=0; nt<4; ++nt) {
      ushort4 a0 = *(const ushort4*)(acc0 + (((size_t)blk01*8 + mt*4 + nt)*256 + tid)*4);
      ushort4 a1 = *(const ushort4*)(acc1 + (((size_t)blk01*8 + mt*4 + nt)*256 + tid)*4);
      oacc[mt][nt][0] = b2f(a0.x) + b2f(a1.x);
      oacc[mt][nt][1] = b2f(a0.y) + b2f(a1.y);
      oacc[mt][nt][2] = b2f(a0.z) + b2f(a1.z);
      oacc[mt][nt][3] = b2f(a0.w) + b2f(a1.w);
    }

  float inv[2][4];
  #pragma unroll
  for (int mt=0; mt<2; ++mt)
    #pragma unroll
    for (int rr=0; rr<4; ++rr) {
      const int s = 16*mt + 4*lg + rr;
      float dsum = 0.f;
      #pragma unroll
      for (int hf=0; hf<2; ++hf)
        #pragma unroll
        for (int w=0; w<4; ++w)
          dsum += den[(((size_t)hf*512 + blk01)*4 + w)*32 + s];
      float f = flr[bhoff + s0 + s];
      inv[mt][rr] = 1.f / (fmaxf(fabsf(dsum), f) + 1e-8f);
    }

  float s1p[2][4] = {{0,0,0,0},{0,0,0,0}}, s2p[2][4] = {{0,0,0,0},{0,0,0,0}};
  #pragma unroll
  for (int mt=0; mt<2; ++mt)
    #pragma unroll
    for (int nt=0; nt<4; ++nt)
      #pragma unroll
      for (int rr=0; rr<4; ++rr) {
        float v = oacc[mt][nt][rr] * inv[mt][rr];
        oacc[mt][nt][rr] = v;
        s1p[mt][rr] += v;
        s2p[mt][rr] += v*v;
      }
  #pragma unroll
  for (int mt=0; mt<2; ++mt)
    #pragma unroll
    for (int rr=0; rr<4; ++rr) {
      float a = s1p[mt][rr], qv = s2p[mt][rr];
      a += __shfl_xor(a, 1); a += __shfl_xor(a, 2);
      a += __shfl_xor(a, 4); a += __shfl_xor(a, 8);
      qv += __shfl_xor(qv, 1); qv += __shfl_xor(qv, 2);
      qv += __shfl_xor(qv, 4); qv += __shfl_xor(qv, 8);
      if (l15 == 0) {
        const int rib = 16*mt + 4*lg + rr;
        smS1[rib*4 + wc] = a;
        smS2[rib*4 + wc] = qv;
      }
    }
  __syncthreads();

  float g4[4];
  #pragma unroll
  for (int nt=0; nt<4; ++nt) g4[nt] = 1.f + ln_w[h*DHH + 64*wc + 16*nt + l15];

  #pragma unroll
  for (int mt=0; mt<2; ++mt)
    #pragma unroll
    for (int rr=0; rr<4; ++rr) {
      const int rib = 16*mt + 4*lg + rr;
      const float ms = smS1[rib*4+0] + smS1[rib*4+1] + smS1[rib*4+2] + smS1[rib*4+3];
      const float sq = smS2[rib*4+0] + smS2[rib*4+1] + smS2[rib*4+2] + smS2[rib*4+3];
      const float mean = ms * (1.f/DHH);
      const float var  = sq * (1.f/DHH) - mean*mean;
      const float rstd = rsqrtf(var + 1e-5f);
      float* op = out + ((size_t)(bB*SS + s0 + rib))*DD + h*DHH;
      #pragma unroll
      for (int nt=0; nt<4; ++nt)
        op[64*wc + 16*nt + l15] = (oacc[mt][nt][rr] - mean)*rstd*g4[nt];
    }
}

// ---------------------------------------------------------------------------
extern "C" void kernel_launch(void* const* d_in, const int* in_sizes, int n_in,
                              void* d_out, int out_size, void* d_ws, size_t ws_size,
                              hipStream_t stream) {
  (void)in_sizes; (void)n_in; (void)out_size; (void)ws_size;
  const float* x    = (const float*)d_in[0];
  const float* wq   = (const float*)d_in[1];
  const float* wk   = (const float*)d_in[2];
  const float* wv   = (const float*)d_in[3];
  const float* wi   = (const float*)d_in[4];
  const float* bi   = (const float*)d_in[5];
  const float* wf   = (const float*)d_in[6];
  const float* bf   = (const float*)d_in[7];
  const float* ln_w = (const float*)d_in[8];
  float* out = (float*)d_out;
  char* ws = (char*)d_ws;

  unsigned short* QB = (unsigned short*)(ws + QB_OFF);
  unsigned short* KB = (unsigned short*)(ws + KB_OFF);
  unsigned short* VB = (unsigned short*)(ws + VB_OFF);
  unsigned short* KF = (unsigned short*)(ws + KF_OFF);
  unsigned short* VF = (unsigned short*)(ws + VF_OFF);
  unsigned short* ACC0 = (unsigned short*)(ws + ACC0_OFF);
  unsigned short* ACC1 = (unsigned short*)(ws + ACC1_OFF);
  float* DEN  = (float*)(ws + DEN_OFF);
  float* IG  = (float*)(ws + IG_OFF);
  float* LSF = (float*)(ws + LSF_OFF);
  float* AA  = (float*)(ws + AA_OFF);
  float* MM  = (float*)(ws + MM_OFF);
  float* FLR = (float*)(ws + FLR_OFF);
  float* WSI = (float*)(ws + WSI_OFF);
  float* WSF = (float*)(ws + WSF_OFF);

  k_gw<<<32, 256, 0, stream>>>(wi, wf, WSI, WSF);
  k_proj<<<512, 256, 0, stream>>>(x, wq, wk, wv, WSI, bi, WSF, bf, QB, KB, VB, IG, LSF);
  k_scan<<<BHH, 256, 0, stream>>>(IG, LSF, AA, MM, FLR);
  k_pack<<<dim3(BHH, SS/64), 256, 0, stream>>>(KB, VB, KF, VF);
  k_attn<<<1024, 256, 0, stream>>>(QB, KF, VF, AA, MM, ACC0, ACC1, DEN);
  k_fin<<<512, 256, 0, stream>>>(ACC0, ACC1, DEN, FLR, ln_w, out);
}

// Round 22
// 81.311 us; speedup vs baseline: 1.0648x; 1.0648x over previous
//
#include <hip/hip_runtime.h>
#include <math.h>

// ---------------------------------------------------------------------------
// mLSTM cell, MFMA bf16. Round 22: revert R21's co-residency map to R20's
// (band = 63-(u>>1), half = u&1): R21's "equal-depth" map concentrated total
// work (deep CU: 64 tiles vs 40) and regressed. Everything else = R20 (best,
// 81.4us): W LDS dbuf + ONE lgkm-only barrier/tile, bf16 partial accum,
// split-K halves, V-hoist pin, 8-row k_proj, fused k_pack.
// ---------------------------------------------------------------------------

#define BB   2
#define SS   2048
#define DD   1024
#define NHH  4
#define DHH  256
#define BHH  (BB*NHH)

// Workspace byte offsets (~49 MB; ACC0 overlays dead KB)
#define QB_OFF   ((size_t)0)
#define KB_OFF   ((size_t)8  << 20)
#define VB_OFF   ((size_t)16 << 20)
#define KF_OFF   ((size_t)24 << 20)
#define VF_OFF   ((size_t)32 << 20)
#define ACC0_OFF ((size_t)8  << 20)   // 8 MB bf16, overlays KB (dead after k_pack)
#define ACC1_OFF ((size_t)40 << 20)   // 8 MB bf16
#define DEN_OFF  ((size_t)48 << 20)   // 512 KB
#define IG_OFF   (DEN_OFF + ((size_t)512<<10))
#define LSF_OFF  (IG_OFF  + ((size_t)64<<10))
#define AA_OFF   (LSF_OFF + ((size_t)64<<10))
#define MM_OFF   (AA_OFF  + ((size_t)64<<10))
#define FLR_OFF  (MM_OFF  + ((size_t)64<<10))
#define WSI_OFF  (FLR_OFF + ((size_t)64<<10))
#define WSF_OFF  (WSI_OFF + ((size_t)32<<10))

typedef __attribute__((ext_vector_type(8))) short short8;   // 8 bf16 (4 VGPR)
typedef __attribute__((ext_vector_type(4))) float f32x4;

__device__ __forceinline__ unsigned short f2b(float f) {
  union { float f; unsigned int u; } v; v.f = f;
  unsigned int r = (v.u + 0x7FFFu + ((v.u >> 16) & 1u)) >> 16;
  return (unsigned short)r;
}
__device__ __forceinline__ float b2f(unsigned short u) {
  union { float f; unsigned int u32; } v; v.u32 = ((unsigned int)u) << 16;
  return v.f;
}
__device__ __forceinline__ float dot4(float4 a, float4 b) {
  return a.x*b.x + a.y*b.y + a.z*b.z + a.w*b.w;
}

// ---------------------------------------------------------------------------
// Kernel 0: gate weight pre-sum.
// ---------------------------------------------------------------------------
__global__ __launch_bounds__(256) void k_gw(
    const float* __restrict__ wi, const float* __restrict__ wf,
    float* __restrict__ wsi, float* __restrict__ wsf)
{
  const int idx = blockIdx.x*256 + threadIdx.x;   // 0..8191
  const int n = idx >> 10, c = idx & 1023;
  wsi[idx] = wi[n*3*DD + c] + wi[n*3*DD + DD + c] + wi[n*3*DD + 2*DD + c];
  wsf[idx] = wf[n*3*DD + c] + wf[n*3*DD + DD + c] + wf[n*3*DD + 2*DD + c];
}

// ---------------------------------------------------------------------------
// Kernel 1: headwise QKV projection + gate GEMVs, 8 rows/block.
// ---------------------------------------------------------------------------
__global__ __launch_bounds__(256) void k_proj(
    const float* __restrict__ x,
    const float* __restrict__ wq, const float* __restrict__ wk, const float* __restrict__ wv,
    const float* __restrict__ wsi, const float* __restrict__ bi,
    const float* __restrict__ wsf, const float* __restrict__ bf,
    unsigned short* __restrict__ qb, unsigned short* __restrict__ kb,
    unsigned short* __restrict__ vb, float* __restrict__ ig, float* __restrict__ lsf)
{
  const int rb = blockIdx.x;           // 0..511, 8 rows each
  const int g  = threadIdx.x;          // qkv head 0..255
  const int h   = g >> 6;
  const int dh0 = (g & 63) << 2;
  const int c   = g << 2;
  const int lane = g & 63, wid = g >> 6;

  const float4 q0 = *(const float4*)(wq + g*16 + 0);
  const float4 q1 = *(const float4*)(wq + g*16 + 4);
  const float4 q2 = *(const float4*)(wq + g*16 + 8);
  const float4 q3 = *(const float4*)(wq + g*16 + 12);
  const float4 k0 = *(const float4*)(wk + g*16 + 0);
  const float4 k1 = *(const float4*)(wk + g*16 + 4);
  const float4 k2 = *(const float4*)(wk + g*16 + 8);
  const float4 k3 = *(const float4*)(wk + g*16 + 12);
  const float4 v0 = *(const float4*)(wv + g*16 + 0);
  const float4 v1 = *(const float4*)(wv + g*16 + 4);
  const float4 v2 = *(const float4*)(wv + g*16 + 8);
  const float4 v3 = *(const float4*)(wv + g*16 + 12);
  const float4 gi0 = *(const float4*)(wsi + 0*DD + c);
  const float4 gi1 = *(const float4*)(wsi + 1*DD + c);
  const float4 gi2 = *(const float4*)(wsi + 2*DD + c);
  const float4 gi3 = *(const float4*)(wsi + 3*DD + c);
  const float4 gf0 = *(const float4*)(wsf + 0*DD + c);
  const float4 gf1 = *(const float4*)(wsf + 1*DD + c);
  const float4 gf2 = *(const float4*)(wsf + 2*DD + c);
  const float4 gf3 = *(const float4*)(wsf + 3*DD + c);

  __shared__ float redI[8][4][4];   // [row][n][wid]
  __shared__ float redF[8][4][4];

  #pragma unroll
  for (int r4 = 0; r4 < 8; ++r4) {
    const int row = rb*8 + r4;
    const int b = row >> 11, s = row & (SS-1);
    const float4 xv = *(const float4*)(x + (size_t)row*DD + c);
    const size_t qi = ((size_t)(b*NHH + h)*SS + s)*DHH + dh0;

    ushort4 r;
    r.x = f2b(dot4(q0,xv)); r.y = f2b(dot4(q1,xv));
    r.z = f2b(dot4(q2,xv)); r.w = f2b(dot4(q3,xv));
    *(ushort4*)(qb + qi) = r;
    r.x = f2b(0.0625f*dot4(k0,xv)); r.y = f2b(0.0625f*dot4(k1,xv));
    r.z = f2b(0.0625f*dot4(k2,xv)); r.w = f2b(0.0625f*dot4(k3,xv));
    *(ushort4*)(kb + qi) = r;
    r.x = f2b(dot4(v0,xv)); r.y = f2b(dot4(v1,xv));
    r.z = f2b(dot4(v2,xv)); r.w = f2b(dot4(v3,xv));
    *(ushort4*)(vb + qi) = r;

    float pi0 = dot4(gi0,xv), pi1 = dot4(gi1,xv), pi2 = dot4(gi2,xv), pi3 = dot4(gi3,xv);
    float pf0 = dot4(gf0,xv), pf1 = dot4(gf1,xv), pf2 = dot4(gf2,xv), pf3 = dot4(gf3,xv);
    #pragma unroll
    for (int off=32; off>0; off>>=1) {
      pi0 += __shfl_down(pi0, off); pi1 += __shfl_down(pi1, off);
      pi2 += __shfl_down(pi2, off); pi3 += __shfl_down(pi3, off);
      pf0 += __shfl_down(pf0, off); pf1 += __shfl_down(pf1, off);
      pf2 += __shfl_down(pf2, off); pf3 += __shfl_down(pf3, off);
    }
    if (lane == 0) {
      redI[r4][0][wid] = pi0; redI[r4][1][wid] = pi1;
      redI[r4][2][wid] = pi2; redI[r4][3][wid] = pi3;
      redF[r4][0][wid] = pf0; redF[r4][1][wid] = pf1;
      redF[r4][2][wid] = pf2; redF[r4][3][wid] = pf3;
    }
  }
  __syncthreads();
  if (g < 32) {
    const int r4 = g >> 2, n = g & 3;
    const int row = rb*8 + r4;
    const int b = row >> 11, s = row & (SS-1);
    float ti = redI[r4][n][0]+redI[r4][n][1]+redI[r4][n][2]+redI[r4][n][3] + bi[n];
    float tf = redF[r4][n][0]+redF[r4][n][1]+redF[r4][n][2]+redF[r4][n][3] + bf[n];
    ig[(size_t)(b*NHH+n)*SS + s] = ti;
    float ls = (tf >= 0.f) ? -log1pf(expf(-tf)) : (tf - log1pf(expf(tf)));
    lsf[(size_t)(b*NHH+n)*SS + s] = ls;
  }
}

// ---------------------------------------------------------------------------
// Kernel 2: per-(b,head) scan.
// ---------------------------------------------------------------------------
__global__ __launch_bounds__(256) void k_scan(
    const float* __restrict__ ig, const float* __restrict__ lsf,
    float* __restrict__ aa, float* __restrict__ mm, float* __restrict__ flr)
{
  const int bh = blockIdx.x;
  const int tid = threadIdx.x;
  const float* igp = ig + (size_t)bh*SS;
  const float* lsp = lsf + (size_t)bh*SS;
  float* ap = aa + (size_t)bh*SS;
  float* mp = mm + (size_t)bh*SS;
  float* fp = flr + (size_t)bh*SS;

  __shared__ float sb[256];
  const int base = tid*8;
  float l[8], c[8];
  #pragma unroll
  for (int j=0;j<8;j++) l[j] = lsp[base+j];
  c[0] = l[0];
  #pragma unroll
  for (int j=1;j<8;j++) c[j] = c[j-1] + l[j];

  sb[tid] = c[7];
  __syncthreads();
  for (int off=1; off<256; off<<=1) {
    float v = sb[tid];
    float u = (tid>=off) ? sb[tid-off] : 0.f;
    __syncthreads();
    sb[tid] = v + u;
    __syncthreads();
  }
  const float exs = (tid==0) ? 0.f : sb[tid-1];

  float cs[8], a8[8], mx[8];
  #pragma unroll
  for (int j=0;j<8;j++) { cs[j] = exs + c[j]; a8[j] = igp[base+j] - cs[j]; }
  mx[0] = a8[0];
  #pragma unroll
  for (int j=1;j<8;j++) mx[j] = fmaxf(mx[j-1], a8[j]);

  __syncthreads();
  sb[tid] = mx[7];
  __syncthreads();
  for (int off=1; off<256; off<<=1) {
    float v = sb[tid];
    float u = (tid>=off) ? sb[tid-off] : -INFINITY;
    __syncthreads();
    sb[tid] = fmaxf(v, u);
    __syncthreads();
  }
  const float exm = (tid==0) ? -INFINITY : sb[tid-1];

  #pragma unroll
  for (int j=0;j<8;j++) {
    float mmx = fmaxf(exm, mx[j]);
    ap[base+j] = a8[j];
    mp[base+j] = mmx;
    fp[base+j] = expf(-(cs[j] + mmx));
  }
}

// ---------------------------------------------------------------------------
// Kernel 3: fused fragment-stream pack (K then V through the same LDS tile).
// ---------------------------------------------------------------------------
__global__ __launch_bounds__(256) void k_pack(
    const unsigned short* __restrict__ kb, const unsigned short* __restrict__ vb,
    unsigned short* __restrict__ kfo, unsigned short* __restrict__ vfo)
{
  __shared__ unsigned short tile[64][264];
  const int bh = blockIdx.x, kt = blockIdx.y;
  const int t0 = kt*64;
  const int tid = threadIdx.x;

  // ---- K ----
  #pragma unroll
  for (int i=0;i<8;i++){
    int f = tid + i*256;
    int r = f >> 5, c = (f & 31)*8;
    *(uint4*)&tile[r][c] = *(const uint4*)(kb + ((size_t)bh*SS + t0 + r)*DHH + c);
  }
  __syncthreads();
  {
    unsigned short* dst = kfo + (size_t)(bh*32 + kt)*16384;
    #pragma unroll
    for (int i=0;i<8;i++){
      int o = tid + i*256;
      int lane = o & 63, g = o >> 6;
      int tt = g >> 3, ks = g & 7;
      int l15 = lane & 15, lg = (lane >> 4) & 3;
      *(uint4*)(dst + (size_t)o*8) = *(const uint4*)&tile[16*tt + l15][32*ks + 8*lg];
    }
  }
  __syncthreads();

  // ---- V ----
  #pragma unroll
  for (int i=0;i<8;i++){
    int f = tid + i*256;
    int r = f >> 5, c = (f & 31)*8;
    *(uint4*)&tile[r][c] = *(const uint4*)(vb + ((size_t)bh*SS + t0 + r)*DHH + c);
  }
  __syncthreads();
  {
    unsigned short* dst = vfo + (size_t)(bh*32 + kt)*16384;
    #pragma unroll
    for (int i=0;i<8;i++){
      int o = tid + i*256;
      int lane = o & 63, g = o >> 6;
      int wc = g >> 3, fi = g & 7;
      int kst = fi >> 2, nt = fi & 3;
      int l15 = lane & 15, lg = (lane >> 4) & 3;
      unsigned short tmp[8];
      #pragma unroll
      for (int j=0;j<8;j++)
        tmp[j] = tile[32*kst + 8*lg + j][64*wc + 16*nt + l15];
      *(uint4*)(dst + (size_t)o*8) = *(uint4*)tmp;
    }
  }
}

// ---------------------------------------------------------------------------
// Kernel 4: MFMA attention, 32-row bands + split-K halves, W double-buffer,
// ONE lgkm-only barrier per tile. 1024 blocks x 256 thr (4 waves).
// R20 map: band = 63-(u>>1), half = u&1 (balanced total work per CU).
// bf16 partial outputs (acc) + fp32 den partials.
// ---------------------------------------------------------------------------
__global__ __launch_bounds__(256) void k_attn(
    const unsigned short* __restrict__ qb, const unsigned short* __restrict__ kfr,
    const unsigned short* __restrict__ vfr,
    const float* __restrict__ ab, const float* __restrict__ mb,
    unsigned short* __restrict__ acc0, unsigned short* __restrict__ acc1,
    float* __restrict__ den)
{
  __shared__ __align__(16) char smW[2*32*128];   // W dbuf: 2 x 32 rows x 128B

  const int bid = blockIdx.x;
  const int bh  = bid & 7;                 // XCD pin
  const int u   = bid >> 3;                // 0..127
  const int band = 63 - (u >> 1);
  const int half = u & 1;
  const int blk01 = bh*64 + band;
  const int s0  = band * 32;
  const int nkt = (32*band + 95) >> 6;     // 1..32
  const int n0  = (nkt + 1) >> 1;
  const int kbeg = half ? n0 : 0;
  const int kend = half ? nkt : n0;

  const int tid  = threadIdx.x;
  const int lane = tid & 63;
  const int wc   = tid >> 6;               // wave 0..3
  const int l15  = lane & 15, lg = lane >> 4;
  const int bhoff = bh * SS;
  const int trel = 16*wc + l15;

  const unsigned short* kfh = kfr + (size_t)bh*32*16384;
  const unsigned short* vfh = vfr + (size_t)bh*32*16384;

  // Q register-resident: 32 rows (two 16-row sub-bands mt)
  short8 qf[2][8];
  {
    const unsigned short* qp = qb + ((size_t)bh*SS + s0)*DHH;
    #pragma unroll
    for (int mt=0; mt<2; ++mt)
      #pragma unroll
      for (int ks=0; ks<8; ++ks)
        qf[mt][ks] = *(const short8*)(qp + (16*mt + l15)*DHH + 32*ks + 8*lg);
  }
  float mrow[2][4];
  #pragma unroll
  for (int mt=0; mt<2; ++mt)
    #pragma unroll
    for (int rr=0; rr<4; ++rr)
      mrow[mt][rr] = mb[bhoff + s0 + 16*mt + 4*lg + rr];

  f32x4 oacc[2][4];
  #pragma unroll
  for (int mt=0; mt<2; ++mt)
    #pragma unroll
    for (int nt=0; nt<4; ++nt)
      oacc[mt][nt] = (f32x4){0.f,0.f,0.f,0.f};
  float denp[2][4] = {{0.f,0.f,0.f,0.f},{0.f,0.f,0.f,0.f}};

  for (int kt = kbeg; kt < kend; ++kt) {
    const int t0 = kt*64;
    char* smWc = smW + ((kt&1)<<12);        // this tile's W slot

    // ---- V(kt) fragment stream + av FIRST (overlap kf latency) ----
    const unsigned short* vfp = vfh + (size_t)kt*16384 + (size_t)wc*4096 + lane*8;
    short8 v0 = *(const short8*)(vfp + 0*512);
    short8 v1 = *(const short8*)(vfp + 1*512);
    short8 v2 = *(const short8*)(vfp + 2*512);
    short8 v3 = *(const short8*)(vfp + 3*512);
    short8 v4 = *(const short8*)(vfp + 4*512);
    short8 v5 = *(const short8*)(vfp + 5*512);
    short8 v6 = *(const short8*)(vfp + 6*512);
    short8 v7 = *(const short8*)(vfp + 7*512);
    const float avC = ab[bhoff + t0 + trel];
    __builtin_amdgcn_sched_barrier(0);   // pin V issue before kf loads

    // ---- QK: kf stream (8 x 1KB coalesced), 16 MFMA (mt=0,1) ----
    f32x4 sacc0 = (f32x4){0.f,0.f,0.f,0.f};
    f32x4 sacc1 = (f32x4){0.f,0.f,0.f,0.f};
    {
      const unsigned short* kfp = kfh + (size_t)kt*16384 + (size_t)wc*4096 + lane*8;
      short8 k0 = *(const short8*)(kfp + 0*512);
      short8 k1 = *(const short8*)(kfp + 1*512);
      short8 k2 = *(const short8*)(kfp + 2*512);
      short8 k3 = *(const short8*)(kfp + 3*512);
      short8 k4 = *(const short8*)(kfp + 4*512);
      short8 k5 = *(const short8*)(kfp + 5*512);
      short8 k6 = *(const short8*)(kfp + 6*512);
      short8 k7 = *(const short8*)(kfp + 7*512);
      __builtin_amdgcn_s_setprio(1);
      sacc0 = __builtin_amdgcn_mfma_f32_16x16x32_bf16(qf[0][0], k0, sacc0, 0,0,0);
      sacc1 = __builtin_amdgcn_mfma_f32_16x16x32_bf16(qf[1][0], k0, sacc1, 0,0,0);
      sacc0 = __builtin_amdgcn_mfma_f32_16x16x32_bf16(qf[0][1], k1, sacc0, 0,0,0);
      sacc1 = __builtin_amdgcn_mfma_f32_16x16x32_bf16(qf[1][1], k1, sacc1, 0,0,0);
      sacc0 = __builtin_amdgcn_mfma_f32_16x16x32_bf16(qf[0][2], k2, sacc0, 0,0,0);
      sacc1 = __builtin_amdgcn_mfma_f32_16x16x32_bf16(qf[1][2], k2, sacc1, 0,0,0);
      sacc0 = __builtin_amdgcn_mfma_f32_16x16x32_bf16(qf[0][3], k3, sacc0, 0,0,0);
      sacc1 = __builtin_amdgcn_mfma_f32_16x16x32_bf16(qf[1][3], k3, sacc1, 0,0,0);
      sacc0 = __builtin_amdgcn_mfma_f32_16x16x32_bf16(qf[0][4], k4, sacc0, 0,0,0);
      sacc1 = __builtin_amdgcn_mfma_f32_16x16x32_bf16(qf[1][4], k4, sacc1, 0,0,0);
      sacc0 = __builtin_amdgcn_mfma_f32_16x16x32_bf16(qf[0][5], k5, sacc0, 0,0,0);
      sacc1 = __builtin_amdgcn_mfma_f32_16x16x32_bf16(qf[1][5], k5, sacc1, 0,0,0);
      sacc0 = __builtin_amdgcn_mfma_f32_16x16x32_bf16(qf[0][6], k6, sacc0, 0,0,0);
      sacc1 = __builtin_amdgcn_mfma_f32_16x16x32_bf16(qf[1][6], k6, sacc1, 0,0,0);
      sacc0 = __builtin_amdgcn_mfma_f32_16x16x32_bf16(qf[0][7], k7, sacc0, 0,0,0);
      sacc1 = __builtin_amdgcn_mfma_f32_16x16x32_bf16(qf[1][7], k7, sacc1, 0,0,0);
      __builtin_amdgcn_s_setprio(0);
    }

    // ---- W = mask * qk * exp(a[t]-m[s]) -> bf16 swizzled LDS slot kt&1 ----
    {
      const bool lastt = (kt == nkt-1);
      #pragma unroll
      for (int mt=0; mt<2; ++mt) {
        #pragma unroll
        for (int rr=0; rr<4; ++rr) {
          const int rib = 16*mt + 4*lg + rr;     // 0..31
          float wv = (mt ? sacc1[rr] : sacc0[rr]) * __expf(avC - mrow[mt][rr]);
          if (lastt && (t0 + trel > s0 + rib)) wv = 0.f;
          denp[mt][rr] += wv;
          *(unsigned short*)(smWc + (size_t)rib*128 + (((trel >> 3) ^ (rib & 7))<<4)
                              + ((trel & 7)<<1)) = f2b(wv);
        }
      }
    }

    // ---- pin V (crosses the barrier) ----
    asm volatile("" :: "v"((int)v0[0]), "v"((int)v1[0]), "v"((int)v2[0]),
                       "v"((int)v3[0]), "v"((int)v4[0]), "v"((int)v5[0]),
                       "v"((int)v6[0]), "v"((int)v7[0]));
    asm volatile("s_waitcnt lgkmcnt(0)" ::: "memory");
    __builtin_amdgcn_s_barrier();
    asm volatile("" ::: "memory");

    // ---- PV: W from LDS slot kt&1 + V from registers, 16 MFMA ----
    // (no trailing barrier: W(kt+2) reuses this slot only after bar(kt+1))
    {
      const int sr0 = l15, sr1 = 16 + l15;
      short8 w00 = *(const short8*)(smWc + (size_t)sr0*128 + ((lg^(sr0&7))<<4));
      short8 w10 = *(const short8*)(smWc + (size_t)sr1*128 + ((lg^(sr1&7))<<4));
      short8 w01 = *(const short8*)(smWc + (size_t)sr0*128 + (((4+lg)^(sr0&7))<<4));
      short8 w11 = *(const short8*)(smWc + (size_t)sr1*128 + (((4+lg)^(sr1&7))<<4));
      __builtin_amdgcn_s_setprio(1);
      oacc[0][0] = __builtin_amdgcn_mfma_f32_16x16x32_bf16(w00, v0, oacc[0][0], 0,0,0);
      oacc[1][0] = __builtin_amdgcn_mfma_f32_16x16x32_bf16(w10, v0, oacc[1][0], 0,0,0);
      oacc[0][1] = __builtin_amdgcn_mfma_f32_16x16x32_bf16(w00, v1, oacc[0][1], 0,0,0);
      oacc[1][1] = __builtin_amdgcn_mfma_f32_16x16x32_bf16(w10, v1, oacc[1][1], 0,0,0);
      oacc[0][2] = __builtin_amdgcn_mfma_f32_16x16x32_bf16(w00, v2, oacc[0][2], 0,0,0);
      oacc[1][2] = __builtin_amdgcn_mfma_f32_16x16x32_bf16(w10, v2, oacc[1][2], 0,0,0);
      oacc[0][3] = __builtin_amdgcn_mfma_f32_16x16x32_bf16(w00, v3, oacc[0][3], 0,0,0);
      oacc[1][3] = __builtin_amdgcn_mfma_f32_16x16x32_bf16(w10, v3, oacc[1][3], 0,0,0);
      oacc[0][0] = __builtin_amdgcn_mfma_f32_16x16x32_bf16(w01, v4, oacc[0][0], 0,0,0);
      oacc[1][0] = __builtin_amdgcn_mfma_f32_16x16x32_bf16(w11, v4, oacc[1][0], 0,0,0);
      oacc[0][1] = __builtin_amdgcn_mfma_f32_16x16x32_bf16(w01, v5, oacc[0][1], 0,0,0);
      oacc[1][1] = __builtin_amdgcn_mfma_f32_16x16x32_bf16(w11, v5, oacc[1][1], 0,0,0);
      oacc[0][2] = __builtin_amdgcn_mfma_f32_16x16x32_bf16(w01, v6, oacc[0][2], 0,0,0);
      oacc[1][2] = __builtin_amdgcn_mfma_f32_16x16x32_bf16(w11, v6, oacc[1][2], 0,0,0);
      oacc[0][3] = __builtin_amdgcn_mfma_f32_16x16x32_bf16(w01, v7, oacc[0][3], 0,0,0);
      oacc[1][3] = __builtin_amdgcn_mfma_f32_16x16x32_bf16(w11, v7, oacc[1][3], 0,0,0);
      __builtin_amdgcn_s_setprio(0);
    }
  }

  // ---- output: den partials (lane-reduced, fp32) + bf16 oacc, coalesced ----
  #pragma unroll
  for (int mt=0; mt<2; ++mt)
    #pragma unroll
    for (int rr=0; rr<4; ++rr) {
      float v = denp[mt][rr];
      v += __shfl_xor(v, 1); v += __shfl_xor(v, 2);
      v += __shfl_xor(v, 4); v += __shfl_xor(v, 8);
      if (l15 == 0)
        den[(((size_t)half*512 + blk01)*4 + wc)*32 + 16*mt + 4*lg + rr] = v;
    }
  unsigned short* accp = half ? acc1 : acc0;
  #pragma unroll
  for (int mt=0; mt<2; ++mt)
    #pragma unroll
    for (int nt=0; nt<4; ++nt) {
      ushort4 r;
      r.x = f2b(oacc[mt][nt][0]); r.y = f2b(oacc[mt][nt][1]);
      r.z = f2b(oacc[mt][nt][2]); r.w = f2b(oacc[mt][nt][3]);
      *(ushort4*)(accp + (((size_t)blk01*8 + mt*4 + nt)*256 + tid)*4) = r;
    }
}

// ---------------------------------------------------------------------------
// Kernel 5: combine halves + normalizer + per-head LayerNorm + write.
// ---------------------------------------------------------------------------
__global__ __launch_bounds__(256) void k_fin(
    const unsigned short* __restrict__ acc0, const unsigned short* __restrict__ acc1,
    const float* __restrict__ den,
    const float* __restrict__ flr, const float* __restrict__ ln_w,
    float* __restrict__ out)
{
  __shared__ float smS1[32*4];
  __shared__ float smS2[32*4];

  const int bid = blockIdx.x;              // 0..511
  const int bh = bid & 7, band = bid >> 3; // band 0..63
  const int blk01 = bh*64 + band;
  const int s0 = band*32;
  const int tid = threadIdx.x;
  const int lane = tid & 63, wc = tid >> 6;
  const int l15 = lane & 15, lg = lane >> 4;
  const int bhoff = bh*SS;
  const int bB = bh >> 2, h = bh & 3;

  f32x4 oacc[2][4];
  #pragma unroll
  for (int mt=0; mt<2; ++mt)
    #pragma unroll
    for (int nt=0; nt<4; ++nt) {
      ushort4 a0 = *(const ushort4*)(acc0 + (((size_t)blk01*8 + mt*4 + nt)*256 + tid)*4);
      ushort4 a1 = *(const ushort4*)(acc1 + (((size_t)blk01*8 + mt*4 + nt)*256 + tid)*4);
      oacc[mt][nt][0] = b2f(a0.x) + b2f(a1.x);
      oacc[mt][nt][1] = b2f(a0.y) + b2f(a1.y);
      oacc[mt][nt][2] = b2f(a0.z) + b2f(a1.z);
      oacc[mt][nt][3] = b2f(a0.w) + b2f(a1.w);
    }

  float inv[2][4];
  #pragma unroll
  for (int mt=0; mt<2; ++mt)
    #pragma unroll
    for (int rr=0; rr<4; ++rr) {
      const int s = 16*mt + 4*lg + rr;
      float dsum = 0.f;
      #pragma unroll
      for (int hf=0; hf<2; ++hf)
        #pragma unroll
        for (int w=0; w<4; ++w)
          dsum += den[(((size_t)hf*512 + blk01)*4 + w)*32 + s];
      float f = flr[bhoff + s0 + s];
      inv[mt][rr] = 1.f / (fmaxf(fabsf(dsum), f) + 1e-8f);
    }

  float s1p[2][4] = {{0,0,0,0},{0,0,0,0}}, s2p[2][4] = {{0,0,0,0},{0,0,0,0}};
  #pragma unroll
  for (int mt=0; mt<2; ++mt)
    #pragma unroll
    for (int nt=0; nt<4; ++nt)
      #pragma unroll
      for (int rr=0; rr<4; ++rr) {
        float v = oacc[mt][nt][rr] * inv[mt][rr];
        oacc[mt][nt][rr] = v;
        s1p[mt][rr] += v;
        s2p[mt][rr] += v*v;
      }
  #pragma unroll
  for (int mt=0; mt<2; ++mt)
    #pragma unroll
    for (int rr=0; rr<4; ++rr) {
      float a = s1p[mt][rr], qv = s2p[mt][rr];
      a += __shfl_xor(a, 1); a += __shfl_xor(a, 2);
      a += __shfl_xor(a, 4); a += __shfl_xor(a, 8);
      qv += __shfl_xor(qv, 1); qv += __shfl_xor(qv, 2);
      qv += __shfl_xor(qv, 4); qv += __shfl_xor(qv, 8);
      if (l15 == 0) {
        const int rib = 16*mt + 4*lg + rr;
        smS1[rib*4 + wc] = a;
        smS2[rib*4 + wc] = qv;
      }
    }
  __syncthreads();

  float g4[4];
  #pragma unroll
  for (int nt=0; nt<4; ++nt) g4[nt] = 1.f + ln_w[h*DHH + 64*wc + 16*nt + l15];

  #pragma unroll
  for (int mt=0; mt<2; ++mt)
    #pragma unroll
    for (int rr=0; rr<4; ++rr) {
      const int rib = 16*mt + 4*lg + rr;
      const float ms = smS1[rib*4+0] + smS1[rib*4+1] + smS1[rib*4+2] + smS1[rib*4+3];
      const float sq = smS2[rib*4+0] + smS2[rib*4+1] + smS2[rib*4+2] + smS2[rib*4+3];
      const float mean = ms * (1.f/DHH);
      const float var  = sq * (1.f/DHH) - mean*mean;
      const float rstd = rsqrtf(var + 1e-5f);
      float* op = out + ((size_t)(bB*SS + s0 + rib))*DD + h*DHH;
      #pragma unroll
      for (int nt=0; nt<4; ++nt)
        op[64*wc + 16*nt + l15] = (oacc[mt][nt][rr] - mean)*rstd*g4[nt];
    }
}

// ---------------------------------------------------------------------------
extern "C" void kernel_launch(void* const* d_in, const int* in_sizes, int n_in,
                              void* d_out, int out_size, void* d_ws, size_t ws_size,
                              hipStream_t stream) {
  (void)in_sizes; (void)n_in; (void)out_size; (void)ws_size;
  const float* x    = (const float*)d_in[0];
  const float* wq   = (const float*)d_in[1];
  const float* wk   = (const float*)d_in[2];
  const float* wv   = (const float*)d_in[3];
  const float* wi   = (const float*)d_in[4];
  const float* bi   = (const float*)d_in[5];
  const float* wf   = (const float*)d_in[6];
  const float* bf   = (const float*)d_in[7];
  const float* ln_w = (const float*)d_in[8];
  float* out = (float*)d_out;
  char* ws = (char*)d_ws;

  unsigned short* QB = (unsigned short*)(ws + QB_OFF);
  unsigned short* KB = (unsigned short*)(ws + KB_OFF);
  unsigned short* VB = (unsigned short*)(ws + VB_OFF);
  unsigned short* KF = (unsigned short*)(ws + KF_OFF);
  unsigned short* VF = (unsigned short*)(ws + VF_OFF);
  unsigned short* ACC0 = (unsigned short*)(ws + ACC0_OFF);
  unsigned short* ACC1 = (unsigned short*)(ws + ACC1_OFF);
  float* DEN  = (float*)(ws + DEN_OFF);
  float* IG  = (float*)(ws + IG_OFF);
  float* LSF = (float*)(ws + LSF_OFF);
  float* AA  = (float*)(ws + AA_OFF);
  float* MM  = (float*)(ws + MM_OFF);
  float* FLR = (float*)(ws + FLR_OFF);
  float* WSI = (float*)(ws + WSI_OFF);
  float* WSF = (float*)(ws + WSF_OFF);

  k_gw<<<32, 256, 0, stream>>>(wi, wf, WSI, WSF);
  k_proj<<<512, 256, 0, stream>>>(x, wq, wk, wv, WSI, bi, WSF, bf, QB, KB, VB, IG, LSF);
  k_scan<<<BHH, 256, 0, stream>>>(IG, LSF, AA, MM, FLR);
  k_pack<<<dim3(BHH, SS/64), 256, 0, stream>>>(KB, VB, KF, VF);
  k_attn<<<1024, 256, 0, stream>>>(QB, KF, VF, AA, MM, ACC0, ACC1, DEN);
  k_fin<<<512, 256, 0, stream>>>(ACC0, ACC1, DEN, FLR, ln_w, out);
}

// Round 23
// 79.662 us; speedup vs baseline: 1.0868x; 1.0207x over previous
//
#include <hip/hip_runtime.h>
#include <math.h>

// ---------------------------------------------------------------------------
// mLSTM cell, MFMA bf16. Round 23: R22 (best, 81.3us) + k_proj writes K
// DIRECTLY in fragment-stream layout (KF) -> k_pack becomes V-only (saves
// 16MB read + 16MB write + half a pass). KF index derivation verified against
// k_pack's: KF[(bh*32+kt)*16384 + ((tt*8+ks)*64+lg*16+l15)*8 + j] =
// K[kt*64+16tt+l15][32ks+8lg+j]; k_proj thread owns (s, d0=(g&63)*4) ->
// one aligned ushort4 slot. All else identical to R22.
// ---------------------------------------------------------------------------

#define BB   2
#define SS   2048
#define DD   1024
#define NHH  4
#define DHH  256
#define BHH  (BB*NHH)

// Workspace byte offsets (~49 MB; ACC0 overlays unused KB region)
#define QB_OFF   ((size_t)0)
#define KB_OFF   ((size_t)8  << 20)   // unused (K goes straight to KF)
#define VB_OFF   ((size_t)16 << 20)
#define KF_OFF   ((size_t)24 << 20)
#define VF_OFF   ((size_t)32 << 20)
#define ACC0_OFF ((size_t)8  << 20)   // 8 MB bf16, overlays KB
#define ACC1_OFF ((size_t)40 << 20)   // 8 MB bf16
#define DEN_OFF  ((size_t)48 << 20)   // 512 KB
#define IG_OFF   (DEN_OFF + ((size_t)512<<10))
#define LSF_OFF  (IG_OFF  + ((size_t)64<<10))
#define AA_OFF   (LSF_OFF + ((size_t)64<<10))
#define MM_OFF   (AA_OFF  + ((size_t)64<<10))
#define FLR_OFF  (MM_OFF  + ((size_t)64<<10))
#define WSI_OFF  (FLR_OFF + ((size_t)64<<10))
#define WSF_OFF  (WSI_OFF + ((size_t)32<<10))

typedef __attribute__((ext_vector_type(8))) short short8;   // 8 bf16 (4 VGPR)
typedef __attribute__((ext_vector_type(4))) float f32x4;

__device__ __forceinline__ unsigned short f2b(float f) {
  union { float f; unsigned int u; } v; v.f = f;
  unsigned int r = (v.u + 0x7FFFu + ((v.u >> 16) & 1u)) >> 16;
  return (unsigned short)r;
}
__device__ __forceinline__ float b2f(unsigned short u) {
  union { float f; unsigned int u32; } v; v.u32 = ((unsigned int)u) << 16;
  return v.f;
}
__device__ __forceinline__ float dot4(float4 a, float4 b) {
  return a.x*b.x + a.y*b.y + a.z*b.z + a.w*b.w;
}

// ---------------------------------------------------------------------------
// Kernel 0: gate weight pre-sum.
// ---------------------------------------------------------------------------
__global__ __launch_bounds__(256) void k_gw(
    const float* __restrict__ wi, const float* __restrict__ wf,
    float* __restrict__ wsi, float* __restrict__ wsf)
{
  const int idx = blockIdx.x*256 + threadIdx.x;   // 0..8191
  const int n = idx >> 10, c = idx & 1023;
  wsi[idx] = wi[n*3*DD + c] + wi[n*3*DD + DD + c] + wi[n*3*DD + 2*DD + c];
  wsf[idx] = wf[n*3*DD + c] + wf[n*3*DD + DD + c] + wf[n*3*DD + 2*DD + c];
}

// ---------------------------------------------------------------------------
// Kernel 1: headwise QKV projection + gate GEMVs, 8 rows/block.
// K written directly in fragment-stream layout (KF); Q,V row-major.
// ---------------------------------------------------------------------------
__global__ __launch_bounds__(256) void k_proj(
    const float* __restrict__ x,
    const float* __restrict__ wq, const float* __restrict__ wk, const float* __restrict__ wv,
    const float* __restrict__ wsi, const float* __restrict__ bi,
    const float* __restrict__ wsf, const float* __restrict__ bf,
    unsigned short* __restrict__ qb, unsigned short* __restrict__ kf,
    unsigned short* __restrict__ vb, float* __restrict__ ig, float* __restrict__ lsf)
{
  const int rb = blockIdx.x;           // 0..511, 8 rows each
  const int g  = threadIdx.x;          // qkv head 0..255
  const int h   = g >> 6;
  const int dh0 = (g & 63) << 2;
  const int c   = g << 2;
  const int lane = g & 63, wid = g >> 6;

  // KF sub-indices from d0 = dh0 (constant per thread)
  const int ksK = dh0 >> 5, lgK = (dh0 >> 3) & 3, j0K = dh0 & 7;

  const float4 q0 = *(const float4*)(wq + g*16 + 0);
  const float4 q1 = *(const float4*)(wq + g*16 + 4);
  const float4 q2 = *(const float4*)(wq + g*16 + 8);
  const float4 q3 = *(const float4*)(wq + g*16 + 12);
  const float4 k0 = *(const float4*)(wk + g*16 + 0);
  const float4 k1 = *(const float4*)(wk + g*16 + 4);
  const float4 k2 = *(const float4*)(wk + g*16 + 8);
  const float4 k3 = *(const float4*)(wk + g*16 + 12);
  const float4 v0 = *(const float4*)(wv + g*16 + 0);
  const float4 v1 = *(const float4*)(wv + g*16 + 4);
  const float4 v2 = *(const float4*)(wv + g*16 + 8);
  const float4 v3 = *(const float4*)(wv + g*16 + 12);
  const float4 gi0 = *(const float4*)(wsi + 0*DD + c);
  const float4 gi1 = *(const float4*)(wsi + 1*DD + c);
  const float4 gi2 = *(const float4*)(wsi + 2*DD + c);
  const float4 gi3 = *(const float4*)(wsi + 3*DD + c);
  const float4 gf0 = *(const float4*)(wsf + 0*DD + c);
  const float4 gf1 = *(const float4*)(wsf + 1*DD + c);
  const float4 gf2 = *(const float4*)(wsf + 2*DD + c);
  const float4 gf3 = *(const float4*)(wsf + 3*DD + c);

  __shared__ float redI[8][4][4];   // [row][n][wid]
  __shared__ float redF[8][4][4];

  #pragma unroll
  for (int r4 = 0; r4 < 8; ++r4) {
    const int row = rb*8 + r4;
    const int b = row >> 11, s = row & (SS-1);
    const float4 xv = *(const float4*)(x + (size_t)row*DD + c);
    const size_t qi = ((size_t)(b*NHH + h)*SS + s)*DHH + dh0;

    ushort4 r;
    r.x = f2b(dot4(q0,xv)); r.y = f2b(dot4(q1,xv));
    r.z = f2b(dot4(q2,xv)); r.w = f2b(dot4(q3,xv));
    *(ushort4*)(qb + qi) = r;
    // K -> fragment-stream layout directly (pre-scaled by 1/16)
    {
      r.x = f2b(0.0625f*dot4(k0,xv)); r.y = f2b(0.0625f*dot4(k1,xv));
      r.z = f2b(0.0625f*dot4(k2,xv)); r.w = f2b(0.0625f*dot4(k3,xv));
      const int kt_ = s >> 6, srel = s & 63;
      const int tt_ = srel >> 4, l15_ = srel & 15;
      const size_t kfi = ((size_t)((b*NHH + h)*32 + kt_))*16384
                       + (size_t)(((tt_*8 + ksK)*64 + lgK*16 + l15_)*8 + j0K);
      *(ushort4*)(kf + kfi) = r;
    }
    r.x = f2b(dot4(v0,xv)); r.y = f2b(dot4(v1,xv));
    r.z = f2b(dot4(v2,xv)); r.w = f2b(dot4(v3,xv));
    *(ushort4*)(vb + qi) = r;

    float pi0 = dot4(gi0,xv), pi1 = dot4(gi1,xv), pi2 = dot4(gi2,xv), pi3 = dot4(gi3,xv);
    float pf0 = dot4(gf0,xv), pf1 = dot4(gf1,xv), pf2 = dot4(gf2,xv), pf3 = dot4(gf3,xv);
    #pragma unroll
    for (int off=32; off>0; off>>=1) {
      pi0 += __shfl_down(pi0, off); pi1 += __shfl_down(pi1, off);
      pi2 += __shfl_down(pi2, off); pi3 += __shfl_down(pi3, off);
      pf0 += __shfl_down(pf0, off); pf1 += __shfl_down(pf1, off);
      pf2 += __shfl_down(pf2, off); pf3 += __shfl_down(pf3, off);
    }
    if (lane == 0) {
      redI[r4][0][wid] = pi0; redI[r4][1][wid] = pi1;
      redI[r4][2][wid] = pi2; redI[r4][3][wid] = pi3;
      redF[r4][0][wid] = pf0; redF[r4][1][wid] = pf1;
      redF[r4][2][wid] = pf2; redF[r4][3][wid] = pf3;
    }
  }
  __syncthreads();
  if (g < 32) {
    const int r4 = g >> 2, n = g & 3;
    const int row = rb*8 + r4;
    const int b = row >> 11, s = row & (SS-1);
    float ti = redI[r4][n][0]+redI[r4][n][1]+redI[r4][n][2]+redI[r4][n][3] + bi[n];
    float tf = redF[r4][n][0]+redF[r4][n][1]+redF[r4][n][2]+redF[r4][n][3] + bf[n];
    ig[(size_t)(b*NHH+n)*SS + s] = ti;
    float ls = (tf >= 0.f) ? -log1pf(expf(-tf)) : (tf - log1pf(expf(tf)));
    lsf[(size_t)(b*NHH+n)*SS + s] = ls;
  }
}

// ---------------------------------------------------------------------------
// Kernel 2: per-(b,head) scan.
// ---------------------------------------------------------------------------
__global__ __launch_bounds__(256) void k_scan(
    const float* __restrict__ ig, const float* __restrict__ lsf,
    float* __restrict__ aa, float* __restrict__ mm, float* __restrict__ flr)
{
  const int bh = blockIdx.x;
  const int tid = threadIdx.x;
  const float* igp = ig + (size_t)bh*SS;
  const float* lsp = lsf + (size_t)bh*SS;
  float* ap = aa + (size_t)bh*SS;
  float* mp = mm + (size_t)bh*SS;
  float* fp = flr + (size_t)bh*SS;

  __shared__ float sb[256];
  const int base = tid*8;
  float l[8], c[8];
  #pragma unroll
  for (int j=0;j<8;j++) l[j] = lsp[base+j];
  c[0] = l[0];
  #pragma unroll
  for (int j=1;j<8;j++) c[j] = c[j-1] + l[j];

  sb[tid] = c[7];
  __syncthreads();
  for (int off=1; off<256; off<<=1) {
    float v = sb[tid];
    float u = (tid>=off) ? sb[tid-off] : 0.f;
    __syncthreads();
    sb[tid] = v + u;
    __syncthreads();
  }
  const float exs = (tid==0) ? 0.f : sb[tid-1];

  float cs[8], a8[8], mx[8];
  #pragma unroll
  for (int j=0;j<8;j++) { cs[j] = exs + c[j]; a8[j] = igp[base+j] - cs[j]; }
  mx[0] = a8[0];
  #pragma unroll
  for (int j=1;j<8;j++) mx[j] = fmaxf(mx[j-1], a8[j]);

  __syncthreads();
  sb[tid] = mx[7];
  __syncthreads();
  for (int off=1; off<256; off<<=1) {
    float v = sb[tid];
    float u = (tid>=off) ? sb[tid-off] : -INFINITY;
    __syncthreads();
    sb[tid] = fmaxf(v, u);
    __syncthreads();
  }
  const float exm = (tid==0) ? -INFINITY : sb[tid-1];

  #pragma unroll
  for (int j=0;j<8;j++) {
    float mmx = fmaxf(exm, mx[j]);
    ap[base+j] = a8[j];
    mp[base+j] = mmx;
    fp[base+j] = expf(-(cs[j] + mmx));
  }
}

// ---------------------------------------------------------------------------
// Kernel 3: V fragment-stream pack (V only; K packed by k_proj directly).
// ---------------------------------------------------------------------------
__global__ __launch_bounds__(256) void k_pack(
    const unsigned short* __restrict__ vb, unsigned short* __restrict__ vfo)
{
  __shared__ unsigned short tile[64][264];
  const int bh = blockIdx.x, kt = blockIdx.y;
  const int t0 = kt*64;
  const int tid = threadIdx.x;

  #pragma unroll
  for (int i=0;i<8;i++){
    int f = tid + i*256;
    int r = f >> 5, c = (f & 31)*8;
    *(uint4*)&tile[r][c] = *(const uint4*)(vb + ((size_t)bh*SS + t0 + r)*DHH + c);
  }
  __syncthreads();
  {
    unsigned short* dst = vfo + (size_t)(bh*32 + kt)*16384;
    #pragma unroll
    for (int i=0;i<8;i++){
      int o = tid + i*256;
      int lane = o & 63, g = o >> 6;
      int wc = g >> 3, fi = g & 7;
      int kst = fi >> 2, nt = fi & 3;
      int l15 = lane & 15, lg = (lane >> 4) & 3;
      unsigned short tmp[8];
      #pragma unroll
      for (int j=0;j<8;j++)
        tmp[j] = tile[32*kst + 8*lg + j][64*wc + 16*nt + l15];
      *(uint4*)(dst + (size_t)o*8) = *(uint4*)tmp;
    }
  }
}

// ---------------------------------------------------------------------------
// Kernel 4: MFMA attention, 32-row bands + split-K halves, W double-buffer,
// ONE lgkm-only barrier per tile. 1024 blocks x 256 thr (4 waves).
// R20 map: band = 63-(u>>1), half = u&1 (balanced total work per CU).
// bf16 partial outputs (acc) + fp32 den partials.
// ---------------------------------------------------------------------------
__global__ __launch_bounds__(256) void k_attn(
    const unsigned short* __restrict__ qb, const unsigned short* __restrict__ kfr,
    const unsigned short* __restrict__ vfr,
    const float* __restrict__ ab, const float* __restrict__ mb,
    unsigned short* __restrict__ acc0, unsigned short* __restrict__ acc1,
    float* __restrict__ den)
{
  __shared__ __align__(16) char smW[2*32*128];   // W dbuf: 2 x 32 rows x 128B

  const int bid = blockIdx.x;
  const int bh  = bid & 7;                 // XCD pin
  const int u   = bid >> 3;                // 0..127
  const int band = 63 - (u >> 1);
  const int half = u & 1;
  const int blk01 = bh*64 + band;
  const int s0  = band * 32;
  const int nkt = (32*band + 95) >> 6;     // 1..32
  const int n0  = (nkt + 1) >> 1;
  const int kbeg = half ? n0 : 0;
  const int kend = half ? nkt : n0;

  const int tid  = threadIdx.x;
  const int lane = tid & 63;
  const int wc   = tid >> 6;               // wave 0..3
  const int l15  = lane & 15, lg = lane >> 4;
  const int bhoff = bh * SS;
  const int trel = 16*wc + l15;

  const unsigned short* kfh = kfr + (size_t)bh*32*16384;
  const unsigned short* vfh = vfr + (size_t)bh*32*16384;

  // Q register-resident: 32 rows (two 16-row sub-bands mt)
  short8 qf[2][8];
  {
    const unsigned short* qp = qb + ((size_t)bh*SS + s0)*DHH;
    #pragma unroll
    for (int mt=0; mt<2; ++mt)
      #pragma unroll
      for (int ks=0; ks<8; ++ks)
        qf[mt][ks] = *(const short8*)(qp + (16*mt + l15)*DHH + 32*ks + 8*lg);
  }
  float mrow[2][4];
  #pragma unroll
  for (int mt=0; mt<2; ++mt)
    #pragma unroll
    for (int rr=0; rr<4; ++rr)
      mrow[mt][rr] = mb[bhoff + s0 + 16*mt + 4*lg + rr];

  f32x4 oacc[2][4];
  #pragma unroll
  for (int mt=0; mt<2; ++mt)
    #pragma unroll
    for (int nt=0; nt<4; ++nt)
      oacc[mt][nt] = (f32x4){0.f,0.f,0.f,0.f};
  float denp[2][4] = {{0.f,0.f,0.f,0.f},{0.f,0.f,0.f,0.f}};

  for (int kt = kbeg; kt < kend; ++kt) {
    const int t0 = kt*64;
    char* smWc = smW + ((kt&1)<<12);        // this tile's W slot

    // ---- V(kt) fragment stream + av FIRST (overlap kf latency) ----
    const unsigned short* vfp = vfh + (size_t)kt*16384 + (size_t)wc*4096 + lane*8;
    short8 v0 = *(const short8*)(vfp + 0*512);
    short8 v1 = *(const short8*)(vfp + 1*512);
    short8 v2 = *(const short8*)(vfp + 2*512);
    short8 v3 = *(const short8*)(vfp + 3*512);
    short8 v4 = *(const short8*)(vfp + 4*512);
    short8 v5 = *(const short8*)(vfp + 5*512);
    short8 v6 = *(const short8*)(vfp + 6*512);
    short8 v7 = *(const short8*)(vfp + 7*512);
    const float avC = ab[bhoff + t0 + trel];
    __builtin_amdgcn_sched_barrier(0);   // pin V issue before kf loads

    // ---- QK: kf stream (8 x 1KB coalesced), 16 MFMA (mt=0,1) ----
    f32x4 sacc0 = (f32x4){0.f,0.f,0.f,0.f};
    f32x4 sacc1 = (f32x4){0.f,0.f,0.f,0.f};
    {
      const unsigned short* kfp = kfh + (size_t)kt*16384 + (size_t)wc*4096 + lane*8;
      short8 k0 = *(const short8*)(kfp + 0*512);
      short8 k1 = *(const short8*)(kfp + 1*512);
      short8 k2 = *(const short8*)(kfp + 2*512);
      short8 k3 = *(const short8*)(kfp + 3*512);
      short8 k4 = *(const short8*)(kfp + 4*512);
      short8 k5 = *(const short8*)(kfp + 5*512);
      short8 k6 = *(const short8*)(kfp + 6*512);
      short8 k7 = *(const short8*)(kfp + 7*512);
      __builtin_amdgcn_s_setprio(1);
      sacc0 = __builtin_amdgcn_mfma_f32_16x16x32_bf16(qf[0][0], k0, sacc0, 0,0,0);
      sacc1 = __builtin_amdgcn_mfma_f32_16x16x32_bf16(qf[1][0], k0, sacc1, 0,0,0);
      sacc0 = __builtin_amdgcn_mfma_f32_16x16x32_bf16(qf[0][1], k1, sacc0, 0,0,0);
      sacc1 = __builtin_amdgcn_mfma_f32_16x16x32_bf16(qf[1][1], k1, sacc1, 0,0,0);
      sacc0 = __builtin_amdgcn_mfma_f32_16x16x32_bf16(qf[0][2], k2, sacc0, 0,0,0);
      sacc1 = __builtin_amdgcn_mfma_f32_16x16x32_bf16(qf[1][2], k2, sacc1, 0,0,0);
      sacc0 = __builtin_amdgcn_mfma_f32_16x16x32_bf16(qf[0][3], k3, sacc0, 0,0,0);
      sacc1 = __builtin_amdgcn_mfma_f32_16x16x32_bf16(qf[1][3], k3, sacc1, 0,0,0);
      sacc0 = __builtin_amdgcn_mfma_f32_16x16x32_bf16(qf[0][4], k4, sacc0, 0,0,0);
      sacc1 = __builtin_amdgcn_mfma_f32_16x16x32_bf16(qf[1][4], k4, sacc1, 0,0,0);
      sacc0 = __builtin_amdgcn_mfma_f32_16x16x32_bf16(qf[0][5], k5, sacc0, 0,0,0);
      sacc1 = __builtin_amdgcn_mfma_f32_16x16x32_bf16(qf[1][5], k5, sacc1, 0,0,0);
      sacc0 = __builtin_amdgcn_mfma_f32_16x16x32_bf16(qf[0][6], k6, sacc0, 0,0,0);
      sacc1 = __builtin_amdgcn_mfma_f32_16x16x32_bf16(qf[1][6], k6, sacc1, 0,0,0);
      sacc0 = __builtin_amdgcn_mfma_f32_16x16x32_bf16(qf[0][7], k7, sacc0, 0,0,0);
      sacc1 = __builtin_amdgcn_mfma_f32_16x16x32_bf16(qf[1][7], k7, sacc1, 0,0,0);
      __builtin_amdgcn_s_setprio(0);
    }

    // ---- W = mask * qk * exp(a[t]-m[s]) -> bf16 swizzled LDS slot kt&1 ----
    {
      const bool lastt = (kt == nkt-1);
      #pragma unroll
      for (int mt=0; mt<2; ++mt) {
        #pragma unroll
        for (int rr=0; rr<4; ++rr) {
          const int rib = 16*mt + 4*lg + rr;     // 0..31
          float wv = (mt ? sacc1[rr] : sacc0[rr]) * __expf(avC - mrow[mt][rr]);
          if (lastt && (t0 + trel > s0 + rib)) wv = 0.f;
          denp[mt][rr] += wv;
          *(unsigned short*)(smWc + (size_t)rib*128 + (((trel >> 3) ^ (rib & 7))<<4)
                              + ((trel & 7)<<1)) = f2b(wv);
        }
      }
    }

    // ---- pin V (crosses the barrier) ----
    asm volatile("" :: "v"((int)v0[0]), "v"((int)v1[0]), "v"((int)v2[0]),
                       "v"((int)v3[0]), "v"((int)v4[0]), "v"((int)v5[0]),
                       "v"((int)v6[0]), "v"((int)v7[0]));
    asm volatile("s_waitcnt lgkmcnt(0)" ::: "memory");
    __builtin_amdgcn_s_barrier();
    asm volatile("" ::: "memory");

    // ---- PV: W from LDS slot kt&1 + V from registers, 16 MFMA ----
    {
      const int sr0 = l15, sr1 = 16 + l15;
      short8 w00 = *(const short8*)(smWc + (size_t)sr0*128 + ((lg^(sr0&7))<<4));
      short8 w10 = *(const short8*)(smWc + (size_t)sr1*128 + ((lg^(sr1&7))<<4));
      short8 w01 = *(const short8*)(smWc + (size_t)sr0*128 + (((4+lg)^(sr0&7))<<4));
      short8 w11 = *(const short8*)(smWc + (size_t)sr1*128 + (((4+lg)^(sr1&7))<<4));
      __builtin_amdgcn_s_setprio(1);
      oacc[0][0] = __builtin_amdgcn_mfma_f32_16x16x32_bf16(w00, v0, oacc[0][0], 0,0,0);
      oacc[1][0] = __builtin_amdgcn_mfma_f32_16x16x32_bf16(w10, v0, oacc[1][0], 0,0,0);
      oacc[0][1] = __builtin_amdgcn_mfma_f32_16x16x32_bf16(w00, v1, oacc[0][1], 0,0,0);
      oacc[1][1] = __builtin_amdgcn_mfma_f32_16x16x32_bf16(w10, v1, oacc[1][1], 0,0,0);
      oacc[0][2] = __builtin_amdgcn_mfma_f32_16x16x32_bf16(w00, v2, oacc[0][2], 0,0,0);
      oacc[1][2] = __builtin_amdgcn_mfma_f32_16x16x32_bf16(w10, v2, oacc[1][2], 0,0,0);
      oacc[0][3] = __builtin_amdgcn_mfma_f32_16x16x32_bf16(w00, v3, oacc[0][3], 0,0,0);
      oacc[1][3] = __builtin_amdgcn_mfma_f32_16x16x32_bf16(w10, v3, oacc[1][3], 0,0,0);
      oacc[0][0] = __builtin_amdgcn_mfma_f32_16x16x32_bf16(w01, v4, oacc[0][0], 0,0,0);
      oacc[1][0] = __builtin_amdgcn_mfma_f32_16x16x32_bf16(w11, v4, oacc[1][0], 0,0,0);
      oacc[0][1] = __builtin_amdgcn_mfma_f32_16x16x32_bf16(w01, v5, oacc[0][1], 0,0,0);
      oacc[1][1] = __builtin_amdgcn_mfma_f32_16x16x32_bf16(w11, v5, oacc[1][1], 0,0,0);
      oacc[0][2] = __builtin_amdgcn_mfma_f32_16x16x32_bf16(w01, v6, oacc[0][2], 0,0,0);
      oacc[1][2] = __builtin_amdgcn_mfma_f32_16x16x32_bf16(w11, v6, oacc[1][2], 0,0,0);
      oacc[0][3] = __builtin_amdgcn_mfma_f32_16x16x32_bf16(w01, v7, oacc[0][3], 0,0,0);
      oacc[1][3] = __builtin_amdgcn_mfma_f32_16x16x32_bf16(w11, v7, oacc[1][3], 0,0,0);
      __builtin_amdgcn_s_setprio(0);
    }
  }

  // ---- output: den partials (lane-reduced, fp32) + bf16 oacc, coalesced ----
  #pragma unroll
  for (int mt=0; mt<2; ++mt)
    #pragma unroll
    for (int rr=0; rr<4; ++rr) {
      float v = denp[mt][rr];
      v += __shfl_xor(v, 1); v += __shfl_xor(v, 2);
      v += __shfl_xor(v, 4); v += __shfl_xor(v, 8);
      if (l15 == 0)
        den[(((size_t)half*512 + blk01)*4 + wc)*32 + 16*mt + 4*lg + rr] = v;
    }
  unsigned short* accp = half ? acc1 : acc0;
  #pragma unroll
  for (int mt=0; mt<2; ++mt)
    #pragma unroll
    for (int nt=0; nt<4; ++nt) {
      ushort4 r;
      r.x = f2b(oacc[mt][nt][0]); r.y = f2b(oacc[mt][nt][1]);
      r.z = f2b(oacc[mt][nt][2]); r.w = f2b(oacc[mt][nt][3]);
      *(ushort4*)(accp + (((size_t)blk01*8 + mt*4 + nt)*256 + tid)*4) = r;
    }
}

// ---------------------------------------------------------------------------
// Kernel 5: combine halves + normalizer + per-head LayerNorm + write.
// ---------------------------------------------------------------------------
__global__ __launch_bounds__(256) void k_fin(
    const unsigned short* __restrict__ acc0, const unsigned short* __restrict__ acc1,
    const float* __restrict__ den,
    const float* __restrict__ flr, const float* __restrict__ ln_w,
    float* __restrict__ out)
{
  __shared__ float smS1[32*4];
  __shared__ float smS2[32*4];

  const int bid = blockIdx.x;              // 0..511
  const int bh = bid & 7, band = bid >> 3; // band 0..63
  const int blk01 = bh*64 + band;
  const int s0 = band*32;
  const int tid = threadIdx.x;
  const int lane = tid & 63, wc = tid >> 6;
  const int l15 = lane & 15, lg = lane >> 4;
  const int bhoff = bh*SS;
  const int bB = bh >> 2, h = bh & 3;

  f32x4 oacc[2][4];
  #pragma unroll
  for (int mt=0; mt<2; ++mt)
    #pragma unroll
    for (int nt=0; nt<4; ++nt) {
      ushort4 a0 = *(const ushort4*)(acc0 + (((size_t)blk01*8 + mt*4 + nt)*256 + tid)*4);
      ushort4 a1 = *(const ushort4*)(acc1 + (((size_t)blk01*8 + mt*4 + nt)*256 + tid)*4);
      oacc[mt][nt][0] = b2f(a0.x) + b2f(a1.x);
      oacc[mt][nt][1] = b2f(a0.y) + b2f(a1.y);
      oacc[mt][nt][2] = b2f(a0.z) + b2f(a1.z);
      oacc[mt][nt][3] = b2f(a0.w) + b2f(a1.w);
    }

  float inv[2][4];
  #pragma unroll
  for (int mt=0; mt<2; ++mt)
    #pragma unroll
    for (int rr=0; rr<4; ++rr) {
      const int s = 16*mt + 4*lg + rr;
      float dsum = 0.f;
      #pragma unroll
      for (int hf=0; hf<2; ++hf)
        #pragma unroll
        for (int w=0; w<4; ++w)
          dsum += den[(((size_t)hf*512 + blk01)*4 + w)*32 + s];
      float f = flr[bhoff + s0 + s];
      inv[mt][rr] = 1.f / (fmaxf(fabsf(dsum), f) + 1e-8f);
    }

  float s1p[2][4] = {{0,0,0,0},{0,0,0,0}}, s2p[2][4] = {{0,0,0,0},{0,0,0,0}};
  #pragma unroll
  for (int mt=0; mt<2; ++mt)
    #pragma unroll
    for (int nt=0; nt<4; ++nt)
      #pragma unroll
      for (int rr=0; rr<4; ++rr) {
        float v = oacc[mt][nt][rr] * inv[mt][rr];
        oacc[mt][nt][rr] = v;
        s1p[mt][rr] += v;
        s2p[mt][rr] += v*v;
      }
  #pragma unroll
  for (int mt=0; mt<2; ++mt)
    #pragma unroll
    for (int rr=0; rr<4; ++rr) {
      float a = s1p[mt][rr], qv = s2p[mt][rr];
      a += __shfl_xor(a, 1); a += __shfl_xor(a, 2);
      a += __shfl_xor(a, 4); a += __shfl_xor(a, 8);
      qv += __shfl_xor(qv, 1); qv += __shfl_xor(qv, 2);
      qv += __shfl_xor(qv, 4); qv += __shfl_xor(qv, 8);
      if (l15 == 0) {
        const int rib = 16*mt + 4*lg + rr;
        smS1[rib*4 + wc] = a;
        smS2[rib*4 + wc] = qv;
      }
    }
  __syncthreads();

  float g4[4];
  #pragma unroll
  for (int nt=0; nt<4; ++nt) g4[nt] = 1.f + ln_w[h*DHH + 64*wc + 16*nt + l15];

  #pragma unroll
  for (int mt=0; mt<2; ++mt)
    #pragma unroll
    for (int rr=0; rr<4; ++rr) {
      const int rib = 16*mt + 4*lg + rr;
      const float ms = smS1[rib*4+0] + smS1[rib*4+1] + smS1[rib*4+2] + smS1[rib*4+3];
      const float sq = smS2[rib*4+0] + smS2[rib*4+1] + smS2[rib*4+2] + smS2[rib*4+3];
      const float mean = ms * (1.f/DHH);
      const float var  = sq * (1.f/DHH) - mean*mean;
      const float rstd = rsqrtf(var + 1e-5f);
      float* op = out + ((size_t)(bB*SS + s0 + rib))*DD + h*DHH;
      #pragma unroll
      for (int nt=0; nt<4; ++nt)
        op[64*wc + 16*nt + l15] = (oacc[mt][nt][rr] - mean)*rstd*g4[nt];
    }
}

// ---------------------------------------------------------------------------
extern "C" void kernel_launch(void* const* d_in, const int* in_sizes, int n_in,
                              void* d_out, int out_size, void* d_ws, size_t ws_size,
                              hipStream_t stream) {
  (void)in_sizes; (void)n_in; (void)out_size; (void)ws_size;
  const float* x    = (const float*)d_in[0];
  const float* wq   = (const float*)d_in[1];
  const float* wk   = (const float*)d_in[2];
  const float* wv   = (const float*)d_in[3];
  const float* wi   = (const float*)d_in[4];
  const float* bi   = (const float*)d_in[5];
  const float* wf   = (const float*)d_in[6];
  const float* bf   = (const float*)d_in[7];
  const float* ln_w = (const float*)d_in[8];
  float* out = (float*)d_out;
  char* ws = (char*)d_ws;

  unsigned short* QB = (unsigned short*)(ws + QB_OFF);
  unsigned short* VB = (unsigned short*)(ws + VB_OFF);
  unsigned short* KF = (unsigned short*)(ws + KF_OFF);
  unsigned short* VF = (unsigned short*)(ws + VF_OFF);
  unsigned short* ACC0 = (unsigned short*)(ws + ACC0_OFF);
  unsigned short* ACC1 = (unsigned short*)(ws + ACC1_OFF);
  float* DEN  = (float*)(ws + DEN_OFF);
  float* IG  = (float*)(ws + IG_OFF);
  float* LSF = (float*)(ws + LSF_OFF);
  float* AA  = (float*)(ws + AA_OFF);
  float* MM  = (float*)(ws + MM_OFF);
  float* FLR = (float*)(ws + FLR_OFF);
  float* WSI = (float*)(ws + WSI_OFF);
  float* WSF = (float*)(ws + WSF_OFF);

  k_gw<<<32, 256, 0, stream>>>(wi, wf, WSI, WSF);
  k_proj<<<512, 256, 0, stream>>>(x, wq, wk, wv, WSI, bi, WSF, bf, QB, KF, VB, IG, LSF);
  k_scan<<<BHH, 256, 0, stream>>>(IG, LSF, AA, MM, FLR);
  k_pack<<<dim3(BHH, SS/64), 256, 0, stream>>>(VB, VF);
  k_attn<<<1024, 256, 0, stream>>>(QB, KF, VF, AA, MM, ACC0, ACC1, DEN);
  k_fin<<<512, 256, 0, stream>>>(ACC0, ACC1, DEN, FLR, ln_w, out);
}